// Round 14
// baseline (84.049 us; speedup 1.0000x reference)
//
#include <hip/hip_runtime.h>
#include <stdint.h>

typedef unsigned short u16;
typedef unsigned int u32;
typedef __attribute__((ext_vector_type(8))) __bf16 bf16x8;
typedef __attribute__((ext_vector_type(4))) float f32x4;
typedef __attribute__((ext_vector_type(2))) float f32x2;

#define B_TOT   32768
#define T_SEQ   96
#define D_IN    7
#define K_LIN   288   // H*T
#define N_LIN   672   // O*T
#define N_PAD   768   // padded N so 128-wide tiles need no load guards

#define LOG2E      1.4426950408889634f
#define TWO_LOG2E  2.8853900817779268f
#define PRSTRIDE   132   // floats per pair-region: 8 steps*16 + 4 pad (bank skew)

// ---------- helpers ----------
__device__ __forceinline__ u16 f2bf(float f) {
  u32 u = __builtin_bit_cast(u32, f);
  u += 0x7fffu + ((u >> 16) & 1u);   // RNE; inputs finite
  return (u16)(u >> 16);
}
// r12-proven DPP via update_dpp builtin (compiler handles DPP hazards).
// CTRL: quad_perm imm (0x00/0x55/0xAA/0xFF broadcasts) or row_ror 0x124/8/C.
template<int CTRL>
__device__ __forceinline__ float rdpp1(float v) {
  int i = __builtin_bit_cast(int, v);
  i = __builtin_amdgcn_update_dpp(0, i, CTRL, 0xF, 0xF, true);
  return __builtin_bit_cast(float, i);
}
template<int CTRL>
__device__ __forceinline__ f32x2 rdpp2(f32x2 v) {
  f32x2 r;
  r.x = rdpp1<CTRL>(v.x);
  r.y = rdpp1<CTRL>(v.y);
  return r;
}

// ---------- kernel 1: pad/convert W_lin -> bf16, k-permuted to j-major ----------
__global__ __launch_bounds__(256) void convert_kernel(
    const float* __restrict__ Wlin, const float* __restrict__ blin,
    u16* __restrict__ Bw, float* __restrict__ biasp)
{
  int i = blockIdx.x * 256 + threadIdx.x;
  if (i < N_PAD * K_LIN) {
    int n = i / K_LIN;
    int kk = i - n * K_LIN;
    int jm = kk / T_SEQ;
    int tm = kk - jm * T_SEQ;
    Bw[i] = f2bf((n < N_LIN) ? Wlin[n * K_LIN + tm * 3 + jm] : 0.0f);
  }
  if (i < N_PAD) biasp[i] = (i < N_LIN) ? blin[i] : 0.0f;
}

// ---------- kernel 2: LSTM, 16 lanes per CHAIN-PAIR, packed f32 (C ops only) ----------
// lane(sub=tid&15): gate g=sub&3, unit quad q=sub>>2 (q==3 = redundant unit-2
// copy, zero-weighted). Lane state f32x2 = {chainA, chainB}. All math via C
// operators on f32x2 (compiler emits v_pk_* or scalar pairs -- correct either
// way); cross-lane via proven update_dpp. Math identical to r12 (passed).
__device__ __forceinline__ void steps8_pk(
    const float* __restrict__ xc,   // &xb[buf][pp*PRSTRIDE], [step][k][2]
    f32x2& h, f32x2& c,
    const f32x2 (&wih)[7], const f32x2 (&whr)[4], f32x2 bias,
    f32x2 sels, f32x2 selb, f32x2* hv8)
{
#pragma unroll
  for (int s = 0; s < 8; ++s) {
    const f32x2* xs = (const f32x2*)(xc + s * 16);
    f32x2 z = bias;
#pragma unroll
    for (int k = 0; k < 7; ++k) z = xs[k] * wih[k] + z;
    // h from the other three unit-quads via DPP row rotates
    f32x2 r1 = rdpp2<0x124>(h);
    f32x2 r2 = rdpp2<0x128>(h);
    f32x2 r3 = rdpp2<0x12C>(h);
    z = h  * whr[0] + z;
    z = r1 * whr[1] + z;
    z = r2 * whr[2] + z;
    z = r3 * whr[3] + z;
    // sigma = rcp(1+exp2(z')), z' = -log2e*z_raw (folded); g-gate: 2*sigma-1
    f32x2 sg;
    sg.x = __builtin_amdgcn_rcpf(1.0f + __builtin_amdgcn_exp2f(z.x));
    sg.y = __builtin_amdgcn_rcpf(1.0f + __builtin_amdgcn_exp2f(z.y));
    f32x2 a = sels * sg + selb;
    // gather i,f,g,o within the unit-quad (quad_perm broadcasts)
    f32x2 ai = rdpp2<0x00>(a);
    f32x2 af = rdpp2<0x55>(a);
    f32x2 ag = rdpp2<0xAA>(a);
    f32x2 ao = rdpp2<0xFF>(a);
    c = af * c + ai * ag;
    f32x2 t;
    t.x = 1.0f - 2.0f * __builtin_amdgcn_rcpf(1.0f + __builtin_amdgcn_exp2f(c.x * TWO_LOG2E));
    t.y = 1.0f - 2.0f * __builtin_amdgcn_rcpf(1.0f + __builtin_amdgcn_exp2f(c.y * TWO_LOG2E));
    f32x2 hv = ao * t;
    hv8[s] = hv;
    h = hv;
  }
}

// interleaved staging write: (A_i, B_i) pairs, 8B each
__device__ __forceinline__ void stw(float* base, const int (&offs)[4],
                                    float4 a, float4 b) {
  f32x2 v;
  v.x = a.x; v.y = b.x; *(f32x2*)(base + offs[0]) = v;
  v.x = a.y; v.y = b.y; *(f32x2*)(base + offs[1]) = v;
  v.x = a.z; v.y = b.z; *(f32x2*)(base + offs[2]) = v;
  v.x = a.w; v.y = b.w; *(f32x2*)(base + offs[3]) = v;
}

__device__ __forceinline__ void wrchunk(u16* hrA, u16* hrB, int n, const f32x2* hv8) {
  u32 a0, a1, a2, a3, c0, c1, c2, c3;
  asm("v_cvt_pk_bf16_f32 %0, %1, %2" : "=v"(a0) : "v"(hv8[0].x), "v"(hv8[1].x));
  asm("v_cvt_pk_bf16_f32 %0, %1, %2" : "=v"(a1) : "v"(hv8[2].x), "v"(hv8[3].x));
  asm("v_cvt_pk_bf16_f32 %0, %1, %2" : "=v"(a2) : "v"(hv8[4].x), "v"(hv8[5].x));
  asm("v_cvt_pk_bf16_f32 %0, %1, %2" : "=v"(a3) : "v"(hv8[6].x), "v"(hv8[7].x));
  asm("v_cvt_pk_bf16_f32 %0, %1, %2" : "=v"(c0) : "v"(hv8[0].y), "v"(hv8[1].y));
  asm("v_cvt_pk_bf16_f32 %0, %1, %2" : "=v"(c1) : "v"(hv8[2].y), "v"(hv8[3].y));
  asm("v_cvt_pk_bf16_f32 %0, %1, %2" : "=v"(c2) : "v"(hv8[4].y), "v"(hv8[5].y));
  asm("v_cvt_pk_bf16_f32 %0, %1, %2" : "=v"(c3) : "v"(hv8[6].y), "v"(hv8[7].y));
  uint4 pa; pa.x = a0; pa.y = a1; pa.z = a2; pa.w = a3;
  uint4 pb; pb.x = c0; pb.y = c1; pb.z = c2; pb.w = c3;
  *(uint4*)(hrA + n * 8) = pa;
  *(uint4*)(hrB + n * 8) = pb;
}

__global__ __launch_bounds__(256, 4) void lstm_kernel(
    const float* __restrict__ x,
    const float* __restrict__ Wih, const float* __restrict__ Whh,
    const float* __restrict__ bih, const float* __restrict__ bhh,
    u16* __restrict__ hs)
{
  __shared__ float sW[132];
  // x double-buffer: [2][16 pairs][PRSTRIDE] = 16.9 KB, [pair][step][k][2]
  __shared__ __align__(16) float xb[2][16 * PRSTRIDE];

  const int tid = threadIdx.x;
  for (int i = tid; i < 132; i += 256) {
    float v; int row;
    if (i < 84)       { v = Wih[i];       row = i / 7; }
    else if (i < 120) { v = Whh[i - 84];  row = (i - 84) / 3; }
    else              { v = bih[i - 120] + bhh[i - 120]; row = i - 120; }
    const int G = row / 3;
    sW[i] = v * ((G == 2) ? -TWO_LOG2E : -LOG2E);   // sigma-form folding
  }
  __syncthreads();

  const int sub = tid & 15;
  const int g   = sub & 3;
  const int q   = sub >> 2;
  const int jj  = (q < 3) ? q : 2;
  const int row = g * 3 + jj;

  // runtime ror-direction probe (r12-proven): delta in {1,3}
  float pv = (float)q;
  float pr = rdpp1<0x124>(pv);
  const int delta = (((int)pr) - q) & 3;

  f32x2 wih[7], whr[4], bias2;
#pragma unroll
  for (int k = 0; k < 7; ++k) { float w = sW[row * 7 + k]; wih[k].x = w; wih[k].y = w; }
  { float b = sW[120 + row]; bias2.x = b; bias2.y = b; }
  {
    float w0 = (q < 3) ? sW[84 + row * 3 + q] : 0.0f;
    whr[0].x = w0; whr[0].y = w0;
#pragma unroll
    for (int r = 1; r < 4; ++r) {
      const int su = (q + r * delta) & 3;
      float w = (su < 3) ? sW[84 + row * 3 + su] : 0.0f;
      whr[r].x = w; whr[r].y = w;
    }
  }
  f32x2 sels, selb;
  { float ss = (g == 2) ? 2.0f : 1.0f, sb = (g == 2) ? -1.0f : 0.0f;
    sels.x = ss; sels.y = ss; selb.x = sb; selb.y = sb; }
  // pin weights in VGPRs (no in-loop LDS remat)
#pragma unroll
  for (int k = 0; k < 7; ++k) asm volatile("" : "+v"(wih[k]));
#pragma unroll
  for (int r = 0; r < 4; ++r) asm volatile("" : "+v"(whr[r]));
  asm volatile("" : "+v"(bias2));

  // staging: 224 threads; thread = (pair p, k-quad sof); loads both chains
  const int b0c = blockIdx.x * 32;          // 32 chains = 16 pairs per block
  const bool stager = (tid < 224);
  const int p   = tid / 14;
  const int sof = (tid % 14) * 4;
  const float* gA = x + (size_t)(b0c + 2 * p) * (T_SEQ * D_IN) + sof;
  const float* gB = gA + T_SEQ * D_IN;
  int offs[4];
#pragma unroll
  for (int i = 0; i < 4; ++i) {
    const int v = sof + i;
    const int s = (v * 9363) >> 16;          // floor(v/7) for v<56 (verified)
    const int k = v - s * 7;
    offs[i] = p * PRSTRIDE + s * 16 + k * 2;
  }

  // compute: group pp = tid>>4 handles pair pp (chains 2pp, 2pp+1)
  const int pp = tid >> 4;
  const float* xc0 = &xb[0][pp * PRSTRIDE];
  const float* xc1 = &xb[1][pp * PRSTRIDE];
  u16* hrA = hs + (size_t)(b0c + 2 * pp) * K_LIN + jj * T_SEQ;
  u16* hrB = hrA + K_LIN;
  const bool writer = (g == 0) && (q < 3);

  f32x2 h = {0.f, 0.f}, c = {0.f, 0.f};
  f32x2 hv8[8];

  // ---- prologue: stage chunk 0 into buf 0 ----
  if (stager) {
    float4 a = *(const float4*)gA;
    float4 b = *(const float4*)gB;
    stw(&xb[0][0], offs, a, b);
  }
  __syncthreads();

  // ---- main loop: 12 chunks of 8 steps, ping-pong buffers ----
#pragma unroll 1
  for (int n2 = 0; n2 < 6; ++n2) {
    const int n = n2 * 2;
    {
      float4 pa = {}, pb = {};
      if (stager) {
        pa = *(const float4*)(gA + (n + 1) * 56);
        pb = *(const float4*)(gB + (n + 1) * 56);
      }
      steps8_pk(xc0, h, c, wih, whr, bias2, sels, selb, hv8);
      __builtin_amdgcn_sched_barrier(0);
      if (stager) stw(&xb[1][0], offs, pa, pb);
      if (writer) wrchunk(hrA, hrB, n, hv8);
      __syncthreads();
    }
    {
      const bool hn = (n2 < 5);
      float4 pa = {}, pb = {};
      if (stager && hn) {
        pa = *(const float4*)(gA + (n + 2) * 56);
        pb = *(const float4*)(gB + (n + 2) * 56);
      }
      steps8_pk(xc1, h, c, wih, whr, bias2, sels, selb, hv8);
      __builtin_amdgcn_sched_barrier(0);
      if (stager && hn) stw(&xb[0][0], offs, pa, pb);
      if (writer) wrchunk(hrA, hrB, n + 1, hv8);
      __syncthreads();
    }
  }
}

// ---------- kernel 3: out = hs(bf16)[32768x288] x Bw^T(bf16)[768x288] + bias ----------
__device__ __forceinline__ void gload16(const u16* g, u16* l) {
  __builtin_amdgcn_global_load_lds(
      (const __attribute__((address_space(1))) void*)g,
      (__attribute__((address_space(3))) void*)l, 16, 0, 0);
}

__global__ __launch_bounds__(256) void gemm_kernel(
    const u16* __restrict__ A, const u16* __restrict__ Bw,
    const float* __restrict__ bias, float* __restrict__ C)
{
  __shared__ u16 As[128 * 32];
  __shared__ u16 Bs[128 * 32];
  const int tid  = threadIdx.x;
  const int lane = tid & 63;
  const int wid  = tid >> 6;
  const int wm = wid >> 1, wn = wid & 1;

  int bx = blockIdx.x;
  int swzb = (bx & 7) * 192 + (bx >> 3);
  const int bm = swzb / 6;
  const int bn = swzb - bm * 6;
  const size_t m0 = (size_t)bm * 128;
  const int n0 = bn * 128;

  const int ra = tid >> 2;
  const int ca = (tid & 3) * 8;
  const u16* ga = A  + (m0 + (size_t)ra) * K_LIN + ca;
  const u16* gb = Bw + (size_t)(n0 + ra) * K_LIN + ca;
  u16* lA = &As[wid * 512];
  u16* lB = &Bs[wid * 512];

  const int l15 = lane & 15, l4 = lane >> 4;
  const u16* pAf = &As[(wm * 64 + l15) * 32 + l4 * 8];
  const u16* pBf = &Bs[(wn * 64 + l15) * 32 + l4 * 8];

  f32x4 acc[4][4] = {};

  for (int kt = 0; kt < 9; ++kt) {
    const int ko = kt * 32;
    gload16(ga + ko,               lA);
    gload16(ga + 64 * K_LIN + ko,  lA + 2048);
    gload16(gb + ko,               lB);
    gload16(gb + 64 * K_LIN + ko,  lB + 2048);
    __syncthreads();
    bf16x8 af[4], bfv[4];
#pragma unroll
    for (int i = 0; i < 4; ++i) af[i]  = *(const bf16x8*)(const void*)(pAf + i * 512);
#pragma unroll
    for (int i = 0; i < 4; ++i) bfv[i] = *(const bf16x8*)(const void*)(pBf + i * 512);
#pragma unroll
    for (int mi = 0; mi < 4; ++mi)
#pragma unroll
      for (int ni = 0; ni < 4; ++ni)
        acc[mi][ni] = __builtin_amdgcn_mfma_f32_16x16x32_bf16(af[mi], bfv[ni], acc[mi][ni], 0, 0, 0);
    __syncthreads();
  }

  float bv[4];
#pragma unroll
  for (int ni = 0; ni < 4; ++ni) bv[ni] = bias[n0 + wn * 64 + ni * 16 + l15];

#pragma unroll
  for (int mi = 0; mi < 4; ++mi) {
#pragma unroll
    for (int ni = 0; ni < 4; ++ni) {
      const int col = n0 + wn * 64 + ni * 16 + l15;
      if (col < N_LIN) {
#pragma unroll
        for (int r = 0; r < 4; ++r) {
          const size_t rowi = m0 + wm * 64 + mi * 16 + l4 * 4 + r;
          C[rowi * N_LIN + col] = acc[mi][ni][r] + bv[ni];
        }
      }
    }
  }
}

extern "C" void kernel_launch(void* const* d_in, const int* in_sizes, int n_in,
                              void* d_out, int out_size, void* d_ws, size_t ws_size,
                              hipStream_t stream) {
  const float* x    = (const float*)d_in[0];
  const float* Wih  = (const float*)d_in[1];
  const float* Whh  = (const float*)d_in[2];
  const float* bih  = (const float*)d_in[3];
  const float* bhh  = (const float*)d_in[4];
  const float* Wlin = (const float*)d_in[5];
  const float* blin = (const float*)d_in[6];
  float* out = (float*)d_out;

  // workspace: hs bf16 [32768][288] | Bw bf16 [768][288] | bias f32 [768]
  u16* hs = (u16*)d_ws;
  u16* Bw = (u16*)((char*)d_ws + (size_t)B_TOT * K_LIN * 2);
  float* biasp = (float*)((char*)d_ws + (size_t)B_TOT * K_LIN * 2 + (size_t)N_PAD * K_LIN * 2);

  convert_kernel<<<(N_PAD * K_LIN + 255) / 256, 256, 0, stream>>>(Wlin, blin, Bw, biasp);
  lstm_kernel<<<B_TOT / 32, 256, 0, stream>>>(x, Wih, Whh, bih, bhh, hs);
  gemm_kernel<<<(B_TOT / 128) * (N_PAD / 128), 256, 0, stream>>>(hs, Bw, biasp, out);
}